// Round 5
// baseline (430.092 us; speedup 1.0000x reference)
//
#include <hip/hip_runtime.h>

#define BATCH 512
#define NNODE 200
#define CIN   200
#define HID   128
#define IPAD  232   // LDS row stride in shorts: 464B rows, 16B-aligned
#define KCH   7     // 7 K-chunks of 32 (cover 224 >= 200)

typedef __attribute__((ext_vector_type(4))) float  f32x4;
typedef __attribute__((ext_vector_type(4))) int    i32x4;
typedef __attribute__((ext_vector_type(8))) short  sh8;
typedef __attribute__((ext_vector_type(4))) short  sh4;
typedef __attribute__((ext_vector_type(8))) __bf16 bf16x8;

__device__ __forceinline__ short f2bf(float x) {
  union { float f; unsigned u; } v; v.f = x;
  unsigned r = v.u + 0x7FFFu + ((v.u >> 16) & 1u);   // RNE
  return (short)(r >> 16);
}
__device__ __forceinline__ float bf2f(short s) {
  union { unsigned u; float f; } v; v.u = ((unsigned)(unsigned short)s) << 16;
  return v.f;
}
__device__ __forceinline__ f32x4 mfma16(sh8 a, sh8 b, f32x4 c) {
  return __builtin_amdgcn_mfma_f32_16x16x32_bf16(
      __builtin_bit_cast(bf16x8, a), __builtin_bit_cast(bf16x8, b), c, 0, 0, 0);
}
__device__ __forceinline__ f32x4 mfma16i(sh8 a, i32x4 b, f32x4 c) {
  return __builtin_amdgcn_mfma_f32_16x16x32_bf16(
      __builtin_bit_cast(bf16x8, a), __builtin_bit_cast(bf16x8, b), c, 0, 0, 0);
}

// ---------- K0: W1 [200][128] fp32 -> W1T [128][232] bf16 (cols [200,232) zeroed) ----------
__global__ void k_w1t(const float* __restrict__ W1, short* __restrict__ W1T) {
  int idx = blockIdx.x * 256 + threadIdx.x;
  if (idx < CIN * HID) {
    int c = idx >> 7, f = idx & 127;
    W1T[f * IPAD + c] = f2bf(W1[idx]);
  } else {
    int q = idx - CIN * HID;
    if (q < HID * (IPAD - CIN)) {
      int f = q / (IPAD - CIN), c = CIN + q % (IPAD - CIN);
      W1T[f * IPAD + c] = 0;
    }
  }
}

// ---------- K_main: one block per batch, 256 threads (4 waves), VGPR budget 256. ----------
// phase A: yT = (x@W1)^T into LDS (MFMA)
// pass 1 : acc[f][j] = sum_i yT[f][i]*adj[i][j] (pure adjacency frags, packed 2/VALU-op)
//          h = relu(acc + (1+e1)*y[j][f] + b1); g[j] = h@W2 (fp32); tile-sum(g) -> LDS atomics
// swap   : yT rows 0..15 -> gT (bf16; rows 2..15 zeroed)
// pass 2 : D2[c][j] = sum_i gT[c][i]*adj[i][j] (adj re-read, L2-hot); sum_j -> sums[2..3]
// epilog : out = b2 + ((1+e2)*sumg + sumagg)/N
__global__ __launch_bounds__(256, 2) void k_main(const float* __restrict__ x,
                                                 const int* __restrict__ adj,
                                                 const short* __restrict__ W1T,
                                                 const float* __restrict__ b1,
                                                 const float* __restrict__ W2,
                                                 const float* __restrict__ b2,
                                                 const float* __restrict__ eps1p,
                                                 const float* __restrict__ eps2p,
                                                 float* __restrict__ out) {
  __shared__ short yT[HID][IPAD];   // 59,392 B (rows 0..15 reused as gT for pass 2)
  __shared__ float gsm[2][NNODE];   //  1,600 B
  __shared__ float b1s[HID];        //    512 B
  __shared__ float W2s[HID][2];     //  1,024 B
  __shared__ float sums[4];         // sumg0, sumg1, sumagg0, sumagg1  -> total 62,544 B

  const int b = blockIdx.x, tid = threadIdx.x;
  const int wave = tid >> 6, lane = tid & 63, lq = lane >> 4, lm = lane & 15;

  // ---- init ----
  for (int i = tid; i < HID * 16; i += 256) {            // zero yT[:, 200:232)
    int f = i >> 4, o = i & 15;
    *(int*)&yT[f][200 + 2 * o] = 0;
  }
  if (tid < HID) { b1s[tid] = b1[tid]; W2s[tid][0] = W2[tid * 2]; W2s[tid][1] = W2[tid * 2 + 1]; }
  if (tid < 4) sums[tid] = 0.f;
  const float e1 = eps1p[0], e2 = eps2p[0];
  const float onep1 = 1.f + e1;

  // ---- phase A: yT = (x @ W1)^T into LDS ----
  const float* xb = x + (size_t)b * NNODE * CIN;
  for (int mt = wave; mt < 13; mt += 4) {
    const int Mbase = mt * 16;
    const int row = min(Mbase + lm, NNODE - 1);
    const float* xr = xb + (size_t)row * CIN;

    sh8 af[KCH];                                         // register-resident (constant-indexed)
#pragma unroll
    for (int k = 0; k < KCH; ++k) {
      const int c0 = k * 32 + lq * 8;
      f32x4 p0 = {0.f,0.f,0.f,0.f}, p1 = {0.f,0.f,0.f,0.f};
      if (c0 < CIN) { p0 = *(const f32x4*)(xr + c0); p1 = *(const f32x4*)(xr + c0 + 4); }
      sh8 a;
#pragma unroll
      for (int jj = 0; jj < 4; ++jj) { a[jj] = f2bf(p0[jj]); a[4 + jj] = f2bf(p1[jj]); }
      af[k] = a;
    }
    for (int ft = 0; ft < 8; ++ft) {
      const int fb = ft * 16;
      const short* wrow = W1T + (size_t)(fb + lm) * IPAD;
      f32x4 acc = {0.f,0.f,0.f,0.f};
#pragma unroll
      for (int k = 0; k < KCH; ++k)
        acc = mfma16(af[k], *(const sh8*)(wrow + k * 32 + lq * 8), acc);
      const int i0 = Mbase + lq * 4;                     // D: n=lm->f, m=lq*4+r->i
      if (i0 + 3 < NNODE) {
        sh4 st;
#pragma unroll
        for (int r = 0; r < 4; ++r) st[r] = f2bf(acc[r]);
        *(sh4*)&yT[fb + lm][i0] = st;
      }
    }
  }
  __syncthreads();

  // ---- pass 1 ----
  const int* adjb = adj + (size_t)b * NNODE * NNODE;
  const unsigned PK = 0x3F80u;                           // bf16(1.0) as packing multiplier
  for (int jt = wave; jt < 13; jt += 4) {
    const int j = jt * 16 + lm;
    const bool jok = (j < NNODE);
    const int jc = min(j, NNODE - 1);

    i32x4 bfr[KCH];                                      // pure adjacency, bf16-packed
#pragma unroll
    for (int k = 0; k < KCH; ++k) {
      const int ib = k * 32 + lq * 8;
      i32x4 w;
#pragma unroll
      for (int h = 0; h < 4; ++h) {
        const int i0 = ib + 2 * h;
        int va = (i0 < NNODE && jok)     ? adjb[i0 * NNODE + j]       : 0;
        int vb = (i0 + 1 < NNODE && jok) ? adjb[(i0 + 1) * NNODE + j] : 0;
        w[h] = (int)(((unsigned)(va | (vb << 16))) * PK);  // 2 bf16 in 2 VALU ops
      }
      bfr[k] = w;
    }

    float ga = 0.f, gb = 0.f;
    for (int ft = 0; ft < 8; ++ft) {
      const int fb = ft * 16;
      f32x4 acc = {0.f,0.f,0.f,0.f};
#pragma unroll
      for (int k = 0; k < KCH; ++k)
        acc = mfma16i(*(const sh8*)&yT[fb + lm][k * 32 + lq * 8], bfr[k], acc);
#pragma unroll
      for (int r = 0; r < 4; ++r) {
        const int f = fb + lq * 4 + r;                   // D[m=f][n=j]
        const float yself = bf2f(yT[f][jc]);             // (1+e1)*y self-term (diag in epilogue)
        float h = fmaxf(acc[r] + onep1 * yself + b1s[f], 0.f);
        ga += h * W2s[f][0];
        gb += h * W2s[f][1];
      }
    }
    ga += __shfl_xor(ga, 16); ga += __shfl_xor(ga, 32);  // full f-sum: lanes<16 hold g[j]
    gb += __shfl_xor(gb, 16); gb += __shfl_xor(gb, 32);
    if (lane < 16 && jok) { gsm[0][j] = ga; gsm[1][j] = gb; }
    float ta = (lane < 16 && jok) ? ga : 0.f;            // once-per-tile sum(g)
    float tb = (lane < 16 && jok) ? gb : 0.f;
#pragma unroll
    for (int d = 1; d < 16; d <<= 1) { ta += __shfl_xor(ta, d); tb += __shfl_xor(tb, d); }
    if (lane == 0) { atomicAdd(&sums[0], ta); atomicAdd(&sums[1], tb); }
  }
  __syncthreads();                                       // pass-1 yT reads done

  // ---- swap: yT rows 0,1 <- g (bf16); rows 2..15 <- 0 (disjoint writes, one barrier) ----
  if (tid < IPAD) {
    yT[0][tid] = (tid < NNODE) ? f2bf(gsm[0][tid]) : (short)0;
    yT[1][tid] = (tid < NNODE) ? f2bf(gsm[1][tid]) : (short)0;
  }
  for (int i = tid; i < 14 * IPAD / 2; i += 256) {       // zero rows 2..15
    int rr = i / (IPAD / 2), o = i % (IPAD / 2);
    *(int*)&yT[2 + rr][2 * o] = 0;
  }
  __syncthreads();

  // ---- pass 2: sum_j (adj^T g)_j ; adj re-read (L2-hot), frags rebuilt ----
  for (int jt = wave; jt < 13; jt += 4) {
    const int j = jt * 16 + lm;
    const bool jok = (j < NNODE);
    f32x4 acc = {0.f,0.f,0.f,0.f};
#pragma unroll
    for (int k = 0; k < KCH; ++k) {
      const int ib = k * 32 + lq * 8;
      i32x4 w;
#pragma unroll
      for (int h = 0; h < 4; ++h) {
        const int i0 = ib + 2 * h;
        int va = (i0 < NNODE && jok)     ? adjb[i0 * NNODE + j]       : 0;
        int vb = (i0 + 1 < NNODE && jok) ? adjb[(i0 + 1) * NNODE + j] : 0;
        w[h] = (int)(((unsigned)(va | (vb << 16))) * PK);
      }
      acc = mfma16i(*(const sh8*)&yT[lm][k * 32 + lq * 8], w, acc);  // A[m=c][k=i], rows>=2 zero
    }
    float v0 = (lq == 0 && jok) ? acc[0] : 0.f;          // D2[c=0][j=lm]
    float v1 = (lq == 0 && jok) ? acc[1] : 0.f;          // D2[c=1][j=lm]
#pragma unroll
    for (int d = 1; d < 16; d <<= 1) { v0 += __shfl_xor(v0, d); v1 += __shfl_xor(v1, d); }
    if (lane == 0) { atomicAdd(&sums[2], v0); atomicAdd(&sums[3], v1); }
  }
  __syncthreads();

  if (tid == 0) {
    out[b * 2 + 0] = b2[0] + ((1.f + e2) * sums[0] + sums[2]) * (1.f / NNODE);
    out[b * 2 + 1] = b2[1] + ((1.f + e2) * sums[1] + sums[3]) * (1.f / NNODE);
  }
}

extern "C" void kernel_launch(void* const* d_in, const int* in_sizes, int n_in,
                              void* d_out, int out_size, void* d_ws, size_t ws_size,
                              hipStream_t stream) {
  const float* x    = (const float*)d_in[0];
  const int*   adj  = (const int*)d_in[1];
  const float* W1   = (const float*)d_in[2];
  const float* b1   = (const float*)d_in[3];
  const float* W2   = (const float*)d_in[4];
  const float* b2   = (const float*)d_in[5];
  const float* eps1 = (const float*)d_in[6];
  const float* eps2 = (const float*)d_in[7];
  float* out = (float*)d_out;

  short* W1T = (short*)d_ws;                             // [128][232] bf16

  k_w1t <<<(HID * IPAD + 255) / 256, 256, 0, stream>>>(W1, W1T);
  k_main<<<BATCH, 256, 0, stream>>>(x, adj, W1T, b1, W2, b2, eps1, eps2, out);
}